// Round 3
// baseline (162.937 us; speedup 1.0000x reference)
//
#include <hip/hip_runtime.h>
#include <hip/hip_bf16.h>

// DenseGATv2: B=4, N=1024, D=128, H=8, QKV=16
// in: h (B,N,D) f32 | same_cluster (B,N,N) int | Wa (2D+1,H) f32 | Wv (D,H*QKV) f32
//     Wo (H*QKV,D) f32 | local_only int scalar
// out: (B,N,D) f32

#define NEG_SLOPE 0.15f
#define B_ 4
#define N_ 1024
#define D_ 128
#define H_ 8
#define QKV_ 16
#define TI 64
#define TJ 64

// ---------------------------------------------------------------------------
// Kernel 1: per 8 rows: stage h row-tile in LDS, compute
//   v = h@Wv  -> V ws laid out (B,H,N,16)
//   s_i = h@Wa[:D], s_j = h@Wa[D:2D] -> SI/SJ ws (B*N,8)
// ---------------------------------------------------------------------------
__global__ __launch_bounds__(256) void prep_kernel(
    const float* __restrict__ h, const float* __restrict__ Wa,
    const float* __restrict__ Wv, float* __restrict__ SI,
    float* __restrict__ SJ, float* __restrict__ V)
{
    __shared__ float hl[8][128];
    const int t  = threadIdx.x;
    const int R0 = blockIdx.x * 8;

    {   // stage 8 rows of h (coalesced float4)
        const int r = t >> 5, k = (t & 31) * 4;
        *(float4*)&hl[r][k] = *(const float4*)(h + (R0 + r) * 128 + k);
    }
    __syncthreads();

    // pass A: v columns. thread (c, g): column c, rows g*4..g*4+3
    const int c = t & 127, g = t >> 7;
    float acc[4] = {0.f, 0.f, 0.f, 0.f};
    #pragma unroll 4
    for (int k = 0; k < 128; ++k) {
        const float wv = Wv[k * 128 + c];
        #pragma unroll
        for (int rr = 0; rr < 4; ++rr)
            acc[rr] += hl[g * 4 + rr][k] * wv;
    }
    const int head = c >> 4, dd = c & 15;
    #pragma unroll
    for (int rr = 0; rr < 4; ++rr) {
        const int R = R0 + g * 4 + rr;
        const int b = R >> 10, n = R & 1023;
        V[((b * H_ + head) * N_ + n) * QKV_ + dd] = acc[rr];
    }

    // pass B: s_i / s_j (128 outputs: 8 rows x (2 which) x 8 heads)
    if (t < 128) {
        const int row = t >> 4, which = (t >> 3) & 1, hh = t & 7;
        const float* wcol = Wa + which * 128 * H_ + hh;
        float s = 0.f;
        #pragma unroll 4
        for (int k = 0; k < 128; ++k)
            s += hl[row][k] * wcol[k * H_];
        const int R = R0 + row;
        float* dst = which ? SJ : SI;
        dst[R * H_ + hh] = s;
    }
}

// ---------------------------------------------------------------------------
// Kernel 2: fused attention per (b, h, i-tile of 64).
// Two-phase per j-chunk of 64: (1) scores+exp -> p_lds, (2) PV from LDS.
// Softmax without max subtraction (scores bounded, exp safe in fp32).
// ---------------------------------------------------------------------------
__global__ __launch_bounds__(256) void attn_kernel(
    const float* __restrict__ SI, const float* __restrict__ SJ,
    const float* __restrict__ V, const int* __restrict__ edge,
    const float* __restrict__ Wa, const int* __restrict__ local_only,
    float* __restrict__ ATT)
{
    const int it = blockIdx.x;      // i-tile
    const int hh = blockIdx.y;      // head
    const int b  = blockIdx.z;
    const int t  = threadIdx.x;
    const int i0 = it * TI;

    __shared__ float si_lds[TI];
    __shared__ float p_lds[TI][TJ + 1];
    __shared__ float v_lds[TJ][QKV_];
    __shared__ float den_lds[TI];

    if (t < TI) si_lds[t] = SI[(b * N_ + i0 + t) * H_ + hh];
    const float we = Wa[2 * D_ * H_ + hh];
    const int   lo = local_only[0];

    // phase-1 mapping: thread = (r = wave id -> i base, j1 = lane -> j)
    const int j1 = t & 63;
    const int r  = t >> 6;
    // phase-2 mapping: thread = (i2, d-group)
    const int i2 = t >> 2;
    const int d0 = (t & 3) * 4;

    float acc[4] = {0.f, 0.f, 0.f, 0.f};
    float dsum[16];
    #pragma unroll
    for (int ii = 0; ii < 16; ++ii) dsum[ii] = 0.f;

    const float* vbase = V + (b * H_ + hh) * N_ * QKV_;
    const int edgebase = (b * N_ + i0) * N_;

    __syncthreads();

    for (int j0 = 0; j0 < N_; j0 += TJ) {
        // stage v chunk (coalesced float4, 1 per thread)
        {
            const int jj = t >> 2, dv = (t & 3) * 4;
            *(float4*)&v_lds[jj][dv] =
                *(const float4*)(vbase + (j0 + jj) * QKV_ + dv);
        }
        const float sj = SJ[(b * N_ + j0 + j1) * H_ + hh];

        // phase 1: scores + exp (each element computed exactly once)
        #pragma unroll
        for (int ii = 0; ii < 16; ++ii) {
            const int i = r + ii * 4;
            const int e = edge[edgebase + i * N_ + j0 + j1];
            float sc = si_lds[i] + sj + (e ? we : 0.f);
            sc = fmaxf(sc, NEG_SLOPE * sc);       // leaky_relu
            float p = __expf(sc);
            if (lo && !e) p = 0.f;                // mask path (local_only)
            p_lds[i][j1] = p;
            dsum[ii] += p;
        }
        __syncthreads();

        // phase 2: y += p * v
        #pragma unroll 8
        for (int jj = 0; jj < TJ; ++jj) {
            const float p  = p_lds[i2][jj];
            const float4 vv = *(const float4*)&v_lds[jj][d0];
            acc[0] += p * vv.x;
            acc[1] += p * vv.y;
            acc[2] += p * vv.z;
            acc[3] += p * vv.w;
        }
        __syncthreads();
    }

    // wave-wide reduce of denominators (wave r owns i = r + 4*ii)
    #pragma unroll
    for (int ii = 0; ii < 16; ++ii) {
        float v = dsum[ii];
        #pragma unroll
        for (int m = 1; m < 64; m <<= 1) v += __shfl_xor(v, m, 64);
        if ((t & 63) == ii) den_lds[r + 4 * ii] = v;
    }
    __syncthreads();

    const float inv = 1.0f / den_lds[i2];
    float4 o;
    o.x = acc[0] * inv; o.y = acc[1] * inv;
    o.z = acc[2] * inv; o.w = acc[3] * inv;
    *(float4*)(ATT + (b * N_ + i0 + i2) * (H_ * QKV_) + hh * QKV_ + d0) = o;
}

// ---------------------------------------------------------------------------
// Kernel 3: out = ATT (B*N,128) @ Wo (128,128)
// ---------------------------------------------------------------------------
__global__ __launch_bounds__(256) void out_kernel(
    const float* __restrict__ ATT, const float* __restrict__ Wo,
    float* __restrict__ out)
{
    __shared__ float al[8][128];
    const int t  = threadIdx.x;
    const int R0 = blockIdx.x * 8;
    {
        const int r = t >> 5, k = (t & 31) * 4;
        *(float4*)&al[r][k] = *(const float4*)(ATT + (R0 + r) * 128 + k);
    }
    __syncthreads();

    const int c = t & 127, g = t >> 7;
    float acc[4] = {0.f, 0.f, 0.f, 0.f};
    #pragma unroll 4
    for (int k = 0; k < 128; ++k) {
        const float w = Wo[k * 128 + c];
        #pragma unroll
        for (int rr = 0; rr < 4; ++rr)
            acc[rr] += al[g * 4 + rr][k] * w;
    }
    #pragma unroll
    for (int rr = 0; rr < 4; ++rr)
        out[(R0 + g * 4 + rr) * 128 + c] = acc[rr];
}

// ---------------------------------------------------------------------------
extern "C" void kernel_launch(void* const* d_in, const int* in_sizes, int n_in,
                              void* d_out, int out_size, void* d_ws, size_t ws_size,
                              hipStream_t stream) {
    const float* h    = (const float*)d_in[0];
    const int*   edge = (const int*)d_in[1];
    const float* Wa   = (const float*)d_in[2];
    const float* Wv   = (const float*)d_in[3];
    const float* Wo   = (const float*)d_in[4];
    const int*   lo   = (const int*)d_in[5];
    float*       out  = (float*)d_out;

    float* ws  = (float*)d_ws;
    float* SI  = ws;                       // B*N*8      = 32768
    float* SJ  = SI + B_ * N_ * H_;        // 32768
    float* V   = SJ + B_ * N_ * H_;        // B*H*N*16   = 524288
    float* ATT = V + B_ * H_ * N_ * QKV_;  // B*N*128    = 524288

    prep_kernel<<<B_ * N_ / 8, 256, 0, stream>>>(h, Wa, Wv, SI, SJ, V);
    attn_kernel<<<dim3(N_ / TI, H_, B_), 256, 0, stream>>>(SI, SJ, V, edge, Wa, lo, ATT);
    out_kernel<<<B_ * N_ / 8, 256, 0, stream>>>(ATT, Wo, out);
}

// Round 6
// 147.579 us; speedup vs baseline: 1.1041x; 1.1041x over previous
//
#include <hip/hip_runtime.h>
#include <hip/hip_bf16.h>

// DenseGATv2: B=4, N=1024, D=128, H=8, QKV=16
// in: h (B,N,D) f32 | same_cluster (B,N,N) int | Wa (2D+1,H) f32 | Wv (D,H*QKV) f32
//     Wo (H*QKV,D) f32 | local_only int scalar
// out: (B,N,D) f32

#define NEG_SLOPE 0.15f
#define B_ 4
#define N_ 1024
#define D_ 128
#define H_ 8
#define QKV_ 16
#define BN_ (B_ * N_)

// ---------------------------------------------------------------------------
// Kernel 1: per 4 rows: stage h rows in LDS, compute
//   v = h@Wv  -> V ws (B,H,N,16)
//   s_i/s_j   -> SIt/SJt ws TRANSPOSED (H, B*N) for coalesced attn reads
// grid = BN/4 = 1024 blocks (4 blocks/CU vs 2 before)
// ---------------------------------------------------------------------------
__global__ __launch_bounds__(256) void prep_kernel(
    const float* __restrict__ h, const float* __restrict__ Wa,
    const float* __restrict__ Wv, float* __restrict__ SIt,
    float* __restrict__ SJt, float* __restrict__ V)
{
    __shared__ float hl[4][128];
    const int t  = threadIdx.x;
    const int R0 = blockIdx.x * 4;

    if (t < 128) {  // stage 4 rows of h (coalesced float4)
        const int r = t >> 5, k = (t & 31) * 4;
        *(float4*)&hl[r][k] = *(const float4*)(h + (R0 + r) * 128 + k);
    }
    __syncthreads();

    // pass A: v columns. thread (c, g): column c, rows g*2..g*2+1
    const int c = t & 127, g = t >> 7;
    float acc0 = 0.f, acc1 = 0.f;
    #pragma unroll 4
    for (int k = 0; k < 128; ++k) {
        const float wv = Wv[k * 128 + c];
        acc0 += hl[g * 2 + 0][k] * wv;
        acc1 += hl[g * 2 + 1][k] * wv;
    }
    const int head = c >> 4, dd = c & 15;
    {
        int R = R0 + g * 2;
        int b = R >> 10, n = R & 1023;
        V[((b * H_ + head) * N_ + n) * QKV_ + dd] = acc0;
        R += 1; b = R >> 10; n = R & 1023;
        V[((b * H_ + head) * N_ + n) * QKV_ + dd] = acc1;
    }

    // pass B: s_i/s_j. 4 rows x 2 which x 8 heads x 4-way k-split = 256 threads
    {
        const int row = t >> 6, which = (t >> 5) & 1, hh = (t >> 2) & 7, q = t & 3;
        const float* wcol = Wa + which * 128 * H_ + hh;
        float s = 0.f;
        #pragma unroll
        for (int kk = 0; kk < 32; ++kk) {
            const int k = q * 32 + kk;
            s += hl[row][k] * wcol[k * H_];
        }
        s += __shfl_xor(s, 1, 64);
        s += __shfl_xor(s, 2, 64);
        if (q == 0) {
            float* dst = which ? SJt : SIt;
            dst[hh * BN_ + R0 + row] = s;
        }
    }
}

// ---------------------------------------------------------------------------
// Kernel 2: fused attention, barrier-free, LDS-free.
// Block = 4 waves; wave owns 4 rows; lane l owns j = j0 + l.
// acc[4][16] register partials (compile-time indexed); one butterfly at end.
// grid = (N/16, H, B) = 2048 blocks.
// ---------------------------------------------------------------------------
__global__ __launch_bounds__(256) void attn_kernel(
    const float* __restrict__ SIt, const float* __restrict__ SJt,
    const float* __restrict__ V, const int* __restrict__ edge,
    const float* __restrict__ Wa, const int* __restrict__ local_only,
    float* __restrict__ ATT)
{
    const int t  = threadIdx.x;
    const int w  = t >> 6;          // wave id 0..3
    const int l  = t & 63;          // lane
    const int hh = blockIdx.y;
    const int b  = blockIdx.z;
    const int i0 = blockIdx.x * 16 + w * 4;   // wave's first row
    const int bn0 = b * N_;

    const float we = Wa[2 * D_ * H_ + hh];
    const int   lo = local_only[0];

    float si[4];
    #pragma unroll
    for (int r = 0; r < 4; ++r) si[r] = SIt[hh * BN_ + bn0 + i0 + r];

    const float* vbase  = V + (size_t)(b * H_ + hh) * N_ * QKV_;
    const float* sjbase = SJt + hh * BN_ + bn0;
    const int*   ebase  = edge + (size_t)(bn0 + i0) * N_;

    float acc[4][16];
    #pragma unroll
    for (int r = 0; r < 4; ++r)
        #pragma unroll
        for (int d = 0; d < 16; ++d) acc[r][d] = 0.f;
    float dsum[4] = {0.f, 0.f, 0.f, 0.f};

    for (int j0 = 0; j0 < N_; j0 += 64) {
        const int j = j0 + l;
        const float sj = sjbase[j];
        const float4* vp = (const float4*)(vbase + j * QKV_);
        const float4 v0 = vp[0], v1 = vp[1], v2 = vp[2], v3 = vp[3];
        int e[4];
        #pragma unroll
        for (int r = 0; r < 4; ++r) e[r] = ebase[r * N_ + j];

        #pragma unroll
        for (int r = 0; r < 4; ++r) {
            float sc = si[r] + sj + (e[r] ? we : 0.f);
            sc = fmaxf(sc, NEG_SLOPE * sc);        // leaky_relu
            float p = __expf(sc);
            if (lo && !e[r]) p = 0.f;              // local_only mask
            dsum[r] += p;
            acc[r][0]  += p * v0.x; acc[r][1]  += p * v0.y;
            acc[r][2]  += p * v0.z; acc[r][3]  += p * v0.w;
            acc[r][4]  += p * v1.x; acc[r][5]  += p * v1.y;
            acc[r][6]  += p * v1.z; acc[r][7]  += p * v1.w;
            acc[r][8]  += p * v2.x; acc[r][9]  += p * v2.y;
            acc[r][10] += p * v2.z; acc[r][11] += p * v2.w;
            acc[r][12] += p * v3.x; acc[r][13] += p * v3.y;
            acc[r][14] += p * v3.z; acc[r][15] += p * v3.w;
        }
    }

    // cross-lane reduce (j was lane-distributed): 6-step butterfly
    #pragma unroll
    for (int r = 0; r < 4; ++r) {
        #pragma unroll
        for (int m = 1; m < 64; m <<= 1) dsum[r] += __shfl_xor(dsum[r], m, 64);
        #pragma unroll
        for (int d = 0; d < 16; ++d) {
            #pragma unroll
            for (int m = 1; m < 64; m <<= 1)
                acc[r][d] += __shfl_xor(acc[r][d], m, 64);
        }
    }

    if (l == 0) {
        #pragma unroll
        for (int r = 0; r < 4; ++r) {
            const float inv = 1.0f / dsum[r];
            float* dst = ATT + (size_t)(bn0 + i0 + r) * 128 + hh * 16;
            #pragma unroll
            for (int q = 0; q < 4; ++q) {
                float4 o;
                o.x = acc[r][4 * q + 0] * inv;
                o.y = acc[r][4 * q + 1] * inv;
                o.z = acc[r][4 * q + 2] * inv;
                o.w = acc[r][4 * q + 3] * inv;
                *(float4*)(dst + 4 * q) = o;
            }
        }
    }
}

// ---------------------------------------------------------------------------
// Kernel 3: out = ATT (B*N,128) @ Wo (128,128). grid = BN/4 = 1024 blocks.
// ---------------------------------------------------------------------------
__global__ __launch_bounds__(256) void out_kernel(
    const float* __restrict__ ATT, const float* __restrict__ Wo,
    float* __restrict__ out)
{
    __shared__ float al[4][128];
    const int t  = threadIdx.x;
    const int R0 = blockIdx.x * 4;
    if (t < 128) {
        const int r = t >> 5, k = (t & 31) * 4;
        *(float4*)&al[r][k] = *(const float4*)(ATT + (R0 + r) * 128 + k);
    }
    __syncthreads();

    const int c = t & 127, g = t >> 7;
    float acc0 = 0.f, acc1 = 0.f;
    #pragma unroll 4
    for (int k = 0; k < 128; ++k) {
        const float w = Wo[k * 128 + c];
        acc0 += al[g * 2 + 0][k] * w;
        acc1 += al[g * 2 + 1][k] * w;
    }
    out[(R0 + g * 2 + 0) * 128 + c] = acc0;
    out[(R0 + g * 2 + 1) * 128 + c] = acc1;
}

// ---------------------------------------------------------------------------
extern "C" void kernel_launch(void* const* d_in, const int* in_sizes, int n_in,
                              void* d_out, int out_size, void* d_ws, size_t ws_size,
                              hipStream_t stream) {
    const float* h    = (const float*)d_in[0];
    const int*   edge = (const int*)d_in[1];
    const float* Wa   = (const float*)d_in[2];
    const float* Wv   = (const float*)d_in[3];
    const float* Wo   = (const float*)d_in[4];
    const int*   lo   = (const int*)d_in[5];
    float*       out  = (float*)d_out;

    float* ws  = (float*)d_ws;
    float* SIt = ws;                       // (H, B*N) = 32768
    float* SJt = SIt + H_ * BN_;           // 32768
    float* V   = SJt + H_ * BN_;           // B*H*N*16 = 524288
    float* ATT = V + (size_t)B_ * H_ * N_ * QKV_;  // B*N*128 = 524288

    prep_kernel<<<BN_ / 4, 256, 0, stream>>>(h, Wa, Wv, SIt, SJt, V);
    attn_kernel<<<dim3(N_ / 16, H_, B_), 256, 0, stream>>>(SIt, SJt, V, edge, Wa, lo, ATT);
    out_kernel<<<BN_ / 4, 256, 0, stream>>>(ATT, Wo, out);
}

// Round 7
// 133.092 us; speedup vs baseline: 1.2242x; 1.1089x over previous
//
#include <hip/hip_runtime.h>
#include <hip/hip_bf16.h>

// DenseGATv2: B=4, N=1024, D=128, H=8, QKV=16
// in: h (B,N,D) f32 | same_cluster (B,N,N) int | Wa (2D+1,H) f32 | Wv (D,H*QKV) f32
//     Wo (H*QKV,D) f32 | local_only int scalar
// out: (B,N,D) f32

#define NEG_SLOPE 0.15f
#define B_ 4
#define N_ 1024
#define D_ 128
#define H_ 8
#define QKV_ 16
#define BN_ (B_ * N_)

// ---------------------------------------------------------------------------
// Kernel 1: 8 rows/block, 512 blocks.
//   pass A: V = h@Wv, thread = 1 row x 4 cols, coalesced float4 W loads,
//           unroll 8 -> 8 loads in flight, ~50 VGPR -> 8 waves/SIMD.
//   pass B: s_i/s_j -> SIt/SJt (H, B*N); 128 dots, 2-way k-split.
// ---------------------------------------------------------------------------
__global__ __launch_bounds__(256) void prep_kernel(
    const float* __restrict__ h, const float* __restrict__ Wa,
    const float* __restrict__ Wv, float* __restrict__ SIt,
    float* __restrict__ SJt, float* __restrict__ V)
{
    __shared__ float hl[8][128];
    const int t  = threadIdx.x;
    const int R0 = blockIdx.x * 8;

    {   // stage 8 rows (1024 floats): 1 float4/thread, coalesced
        const int f = t * 4;
        *(float4*)(&hl[0][0] + f) = *(const float4*)(h + R0 * 128 + f);
    }
    __syncthreads();

    // pass A: thread (cq, rq): row rq, cols cq*4..+3
    const int cq = t & 31, rq = t >> 5;
    const int c4 = cq * 4;
    float acc0 = 0.f, acc1 = 0.f, acc2 = 0.f, acc3 = 0.f;
    #pragma unroll 8
    for (int k = 0; k < 128; ++k) {
        const float4 w = *(const float4*)(Wv + k * 128 + c4);
        const float a = hl[rq][k];
        acc0 += a * w.x; acc1 += a * w.y; acc2 += a * w.z; acc3 += a * w.w;
    }
    {
        const int R = R0 + rq, b = R >> 10, n = R & 1023;
        const int head = cq >> 2, dd = (cq & 3) * 4;
        float4 o; o.x = acc0; o.y = acc1; o.z = acc2; o.w = acc3;
        *(float4*)(V + ((size_t)(b * H_ + head) * N_ + n) * QKV_ + dd) = o;
    }

    // pass B: task = (row, which, hh), 2-way k-split
    {
        const int task = t >> 1, half = t & 1;
        const int row = task >> 4, which = (task >> 3) & 1, hh = task & 7;
        const float* wcol = Wa + which * 128 * H_ + hh;
        float s = 0.f;
        #pragma unroll 8
        for (int kk = 0; kk < 64; ++kk) {
            const int k = half * 64 + kk;
            s += hl[row][k] * wcol[k * H_];
        }
        s += __shfl_xor(s, 1, 64);
        if (!half) {
            float* dst = which ? SJt : SIt;
            dst[hh * BN_ + R0 + row] = s;
        }
    }
}

// ---------------------------------------------------------------------------
// Kernel 2: fused attention, barrier-free, LDS-free.
// Wave owns 4 rows; lane l owns j = j0 + l. unroll 2 for load/compute overlap.
// Final reduce: value-splitting tree (not full butterfly); distributed store.
// grid = (N/16, H, B) = 2048 blocks. VGPR capped 128 (4 waves/SIMD).
// ---------------------------------------------------------------------------
__global__ __launch_bounds__(256, 4) void attn_kernel(
    const float* __restrict__ SIt, const float* __restrict__ SJt,
    const float* __restrict__ V, const int* __restrict__ edge,
    const float* __restrict__ Wa, const int* __restrict__ local_only,
    float* __restrict__ ATT)
{
    const int t  = threadIdx.x;
    const int w  = t >> 6;          // wave id 0..3
    const int l  = t & 63;          // lane
    const int hh = blockIdx.y;
    const int b  = blockIdx.z;
    const int i0 = blockIdx.x * 16 + w * 4;   // wave's first row
    const int bn0 = b * N_;

    const float we = Wa[2 * D_ * H_ + hh];
    const int   lo = local_only[0];

    float si[4];
    #pragma unroll
    for (int r = 0; r < 4; ++r) si[r] = SIt[hh * BN_ + bn0 + i0 + r];

    const float* vbase  = V + (size_t)(b * H_ + hh) * N_ * QKV_;
    const float* sjbase = SJt + hh * BN_ + bn0;
    const int*   ebase  = edge + (size_t)(bn0 + i0) * N_;

    float acc[4][16];
    #pragma unroll
    for (int r = 0; r < 4; ++r)
        #pragma unroll
        for (int d = 0; d < 16; ++d) acc[r][d] = 0.f;
    float dsum[4] = {0.f, 0.f, 0.f, 0.f};

    #pragma unroll 2
    for (int j0 = 0; j0 < N_; j0 += 64) {
        const int j = j0 + l;
        const float sj = sjbase[j];
        const float4* vp = (const float4*)(vbase + j * QKV_);
        const float4 v0 = vp[0], v1 = vp[1], v2 = vp[2], v3 = vp[3];
        int e[4];
        #pragma unroll
        for (int r = 0; r < 4; ++r) e[r] = ebase[r * N_ + j];

        #pragma unroll
        for (int r = 0; r < 4; ++r) {
            float sc = si[r] + sj + (e[r] ? we : 0.f);
            sc = fmaxf(sc, NEG_SLOPE * sc);        // leaky_relu
            float p = __expf(sc);
            if (lo && !e[r]) p = 0.f;              // local_only mask
            dsum[r] += p;
            acc[r][0]  += p * v0.x; acc[r][1]  += p * v0.y;
            acc[r][2]  += p * v0.z; acc[r][3]  += p * v0.w;
            acc[r][4]  += p * v1.x; acc[r][5]  += p * v1.y;
            acc[r][6]  += p * v1.z; acc[r][7]  += p * v1.w;
            acc[r][8]  += p * v2.x; acc[r][9]  += p * v2.y;
            acc[r][10] += p * v2.z; acc[r][11] += p * v2.w;
            acc[r][12] += p * v3.x; acc[r][13] += p * v3.y;
            acc[r][14] += p * v3.z; acc[r][15] += p * v3.w;
        }
    }

    // value-splitting tree reduce: after 4 split steps lane l holds the
    // group-sum of original index (l&15); 2 scalar steps finish 64 lanes.
    const bool b3 = (l & 8) != 0;
    const bool b2 = (l & 4) != 0;
    const bool b1 = (l & 2) != 0;
    const bool b0 = (l & 1) != 0;
    float red[4];
    #pragma unroll
    for (int r = 0; r < 4; ++r) {
        // denominator: plain butterfly (scalar)
        float ds = dsum[r];
        #pragma unroll
        for (int m = 1; m < 64; m <<= 1) ds += __shfl_xor(ds, m, 64);
        dsum[r] = ds;

        float t8[8];
        #pragma unroll
        for (int d = 0; d < 8; ++d) {
            const float keep = b3 ? acc[r][d + 8] : acc[r][d];
            const float send = b3 ? acc[r][d]     : acc[r][d + 8];
            t8[d] = keep + __shfl_xor(send, 8, 64);
        }
        float t4[4];
        #pragma unroll
        for (int d = 0; d < 4; ++d) {
            const float keep = b2 ? t8[d + 4] : t8[d];
            const float send = b2 ? t8[d]     : t8[d + 4];
            t4[d] = keep + __shfl_xor(send, 4, 64);
        }
        float t2[2];
        #pragma unroll
        for (int d = 0; d < 2; ++d) {
            const float keep = b1 ? t4[d + 2] : t4[d];
            const float send = b1 ? t4[d]     : t4[d + 2];
            t2[d] = keep + __shfl_xor(send, 2, 64);
        }
        float t1;
        {
            const float keep = b0 ? t2[1] : t2[0];
            const float send = b0 ? t2[0] : t2[1];
            t1 = keep + __shfl_xor(send, 1, 64);
        }
        t1 += __shfl_xor(t1, 16, 64);
        t1 += __shfl_xor(t1, 32, 64);
        red[r] = t1;   // lane l: S_r[l & 15]
    }

    // distributed store: lane l -> row (l>>4), col (l&15); all 64 lanes store
    {
        const int rsel = l >> 4;
        const float num = rsel == 0 ? red[0] : rsel == 1 ? red[1]
                        : rsel == 2 ? red[2] : red[3];
        const float den = rsel == 0 ? dsum[0] : rsel == 1 ? dsum[1]
                        : rsel == 2 ? dsum[2] : dsum[3];
        ATT[(size_t)(bn0 + i0 + rsel) * 128 + hh * 16 + (l & 15)] = num / den;
    }
}

// ---------------------------------------------------------------------------
// Kernel 3: out = ATT (B*N,128) @ Wo (128,128). 8 rows/block, 512 blocks.
// thread = 1 row x 4 cols; unroll 8; ~50 VGPR -> 8 waves/SIMD.
// ---------------------------------------------------------------------------
__global__ __launch_bounds__(256) void out_kernel(
    const float* __restrict__ ATT, const float* __restrict__ Wo,
    float* __restrict__ out)
{
    __shared__ float al[8][128];
    const int t  = threadIdx.x;
    const int R0 = blockIdx.x * 8;
    {
        const int f = t * 4;
        *(float4*)(&al[0][0] + f) = *(const float4*)(ATT + (size_t)R0 * 128 + f);
    }
    __syncthreads();

    const int cq = t & 31, rq = t >> 5;
    const int c4 = cq * 4;
    float acc0 = 0.f, acc1 = 0.f, acc2 = 0.f, acc3 = 0.f;
    #pragma unroll 8
    for (int k = 0; k < 128; ++k) {
        const float4 w = *(const float4*)(Wo + k * 128 + c4);
        const float a = al[rq][k];
        acc0 += a * w.x; acc1 += a * w.y; acc2 += a * w.z; acc3 += a * w.w;
    }
    float4 o; o.x = acc0; o.y = acc1; o.z = acc2; o.w = acc3;
    *(float4*)(out + (size_t)(R0 + rq) * 128 + c4) = o;
}

// ---------------------------------------------------------------------------
extern "C" void kernel_launch(void* const* d_in, const int* in_sizes, int n_in,
                              void* d_out, int out_size, void* d_ws, size_t ws_size,
                              hipStream_t stream) {
    const float* h    = (const float*)d_in[0];
    const int*   edge = (const int*)d_in[1];
    const float* Wa   = (const float*)d_in[2];
    const float* Wv   = (const float*)d_in[3];
    const float* Wo   = (const float*)d_in[4];
    const int*   lo   = (const int*)d_in[5];
    float*       out  = (float*)d_out;

    float* ws  = (float*)d_ws;
    float* SIt = ws;                       // (H, B*N) = 32768
    float* SJt = SIt + H_ * BN_;           // 32768
    float* V   = SJt + H_ * BN_;           // B*H*N*16 = 524288
    float* ATT = V + (size_t)B_ * H_ * N_ * QKV_;  // B*N*128 = 524288

    prep_kernel<<<BN_ / 8, 256, 0, stream>>>(h, Wa, Wv, SIt, SJt, V);
    attn_kernel<<<dim3(N_ / 16, H_, B_), 256, 0, stream>>>(SIt, SJt, V, edge, Wa, lo, ATT);
    out_kernel<<<BN_ / 8, 256, 0, stream>>>(ATT, Wo, out);
}

// Round 9
// 125.065 us; speedup vs baseline: 1.3028x; 1.0642x over previous
//
#include <hip/hip_runtime.h>
#include <hip/hip_bf16.h>
#include <hip/hip_fp16.h>

// DenseGATv2: B=4, N=1024, D=128, H=8, QKV=16
// in: h (B,N,D) f32 | same_cluster (B,N,N) int | Wa (2D+1,H) f32 | Wv (D,H*QKV) f32
//     Wo (H*QKV,D) f32 | local_only int scalar
// out: (B,N,D) f32

#define NEG_SLOPE 0.15f
#define LOG2E 1.442695040888963f
#define B_ 4
#define N_ 1024
#define D_ 128
#define H_ 8
#define QKV_ 16
#define BN_ (B_ * N_)

typedef _Float16 half8 __attribute__((ext_vector_type(8)));
typedef float f32x4 __attribute__((ext_vector_type(4)));

// ws layout (floats):
//   SIt (H,B*N) 32768 | SJt 32768 | ATT (B*N,128) 524288 | then VT f16 (B,H,16,N)
#define WS_F32_COUNT (32768 + 32768 + 524288)
#define WS_BYTES ((size_t)WS_F32_COUNT * 4 + (size_t)B_ * H_ * 16 * N_ * 2)

// ---------------------------------------------------------------------------
// Kernel 1: 8 rows/block, 512 blocks.
//   pass A: V = h@Wv -> VT f16, TRANSPOSED (B,H, d 0..15, N) for MFMA B-frags
//   pass B: s_i/s_j * LOG2E -> SIt/SJt (H, B*N)  (pre-scaled for exp2)
// ---------------------------------------------------------------------------
__global__ __launch_bounds__(256) void prep_kernel(
    const float* __restrict__ h, const float* __restrict__ Wa,
    const float* __restrict__ Wv, float* __restrict__ SIt,
    float* __restrict__ SJt, _Float16* __restrict__ VT)
{
    __shared__ float hl[8][128];
    const int t  = threadIdx.x;
    const int R0 = blockIdx.x * 8;

    {   // stage 8 rows (1024 floats): 1 float4/thread, coalesced
        const int f = t * 4;
        *(float4*)(&hl[0][0] + f) = *(const float4*)(h + (size_t)R0 * 128 + f);
    }
    __syncthreads();

    // pass A: thread (cq, rq): row rq, cols cq*4..+3 of h@Wv
    const int cq = t & 31, rq = t >> 5;
    const int c4 = cq * 4;
    float a0 = 0.f, a1 = 0.f, a2 = 0.f, a3 = 0.f;
    #pragma unroll 8
    for (int k = 0; k < 128; ++k) {
        const float4 wv = *(const float4*)(Wv + k * 128 + c4);
        const float a = hl[rq][k];
        a0 += a * wv.x; a1 += a * wv.y; a2 += a * wv.z; a3 += a * wv.w;
    }
    {
        const int R = R0 + rq, b = R >> 10, n = R & 1023;
        const int head = cq >> 2, dd = (cq & 3) * 4;
        _Float16* vt = VT + ((size_t)(b * H_ + head) * 16 + dd) * N_ + n;
        vt[0]      = (_Float16)a0;
        vt[N_]     = (_Float16)a1;
        vt[2 * N_] = (_Float16)a2;
        vt[3 * N_] = (_Float16)a3;
    }

    // pass B: task = (row, which, hh), 2-way k-split; store s * LOG2E
    {
        const int task = t >> 1, half = t & 1;
        const int row = task >> 4, which = (task >> 3) & 1, hh = task & 7;
        const float* wcol = Wa + which * 128 * H_ + hh;
        float s = 0.f;
        #pragma unroll 8
        for (int kk = 0; kk < 64; ++kk) {
            const int k = half * 64 + kk;
            s += hl[row][k] * wcol[k * H_];
        }
        s += __shfl_xor(s, 1, 64);
        if (!half) {
            float* dst = which ? SJt : SIt;
            dst[hh * BN_ + R0 + row] = s * LOG2E;
        }
    }
}

// ---------------------------------------------------------------------------
// Kernel 2: fused attention with MFMA PV.
// Block = 16 i-rows x head x batch; wave w owns j in [w*256,(w+1)*256).
// Per 32-j chunk: lanes compute P directly in the A-fragment layout of
// mfma_f32_16x16x32_f16 (lane: row=l&15, k=8*(l>>4)+u), B-frag = one 16B
// load from VT[d][j] (d=l&15). One MFMA replaces 512 scalar FMAs.
// Epilogue: 4-wave reduce of 16x16 O-tiles + denominators via LDS (1 barrier).
// grid = (N/16, H, B) = 2048 blocks.
// ---------------------------------------------------------------------------
__global__ __launch_bounds__(256) void attn_kernel(
    const float* __restrict__ SIt, const float* __restrict__ SJt,
    const _Float16* __restrict__ VT, const int* __restrict__ edge,
    const float* __restrict__ Wa, const int* __restrict__ local_only,
    float* __restrict__ ATT)
{
    const int t  = threadIdx.x;
    const int w  = t >> 6;          // wave id 0..3 (j-quarter)
    const int l  = t & 63;          // lane
    const int m  = l & 15;          // A row (i) / B col (d)
    const int kq = l >> 4;          // k-quad within 32-j chunk
    const int hh = blockIdx.y;
    const int b  = blockIdx.z;
    const int i0 = blockIdx.x * 16;
    const int bn0 = b * N_;

    const float we = Wa[2 * D_ * H_ + hh] * LOG2E;
    const int   lo = local_only[0];

    const float sim   = SIt[hh * BN_ + bn0 + i0 + m];   // pre-scaled by LOG2E
    const float simwe = sim + we;
    const float simNE = lo ? -1e6f : sim;               // local_only: p -> 0

    const float*    sjrow = SJt + hh * BN_ + bn0;       // pre-scaled by LOG2E
    const int*      erow  = edge + (size_t)(bn0 + i0 + m) * N_;
    const _Float16* vrow  = VT + ((size_t)(b * H_ + hh) * 16 + m) * N_;

    f32x4 acc = {0.f, 0.f, 0.f, 0.f};
    float dsum = 0.f;

    const int wj0 = w * 256;
    #pragma unroll 2
    for (int c = 0; c < 8; ++c) {
        const int jb = wj0 + c * 32 + kq * 8;           // lane's 8 j's
        const float4 sjA = *(const float4*)(sjrow + jb);
        const float4 sjB = *(const float4*)(sjrow + jb + 4);
        const int4   eA  = *(const int4*)(erow + jb);
        const int4   eB  = *(const int4*)(erow + jb + 4);
        const half8  bf  = *(const half8*)(vrow + jb);  // B-frag: V[j][d=m]

        const float sj[8] = {sjA.x, sjA.y, sjA.z, sjA.w,
                             sjB.x, sjB.y, sjB.z, sjB.w};
        const int   ee[8] = {eA.x, eA.y, eA.z, eA.w,
                             eB.x, eB.y, eB.z, eB.w};
        half8 av;
        #pragma unroll
        for (int u = 0; u < 8; ++u) {
            const float x  = (ee[u] ? simwe : simNE) + sj[u];
            const float sc = fmaxf(x, NEG_SLOPE * x);   // leaky_relu (log2-dom)
            const float p  = exp2f(sc);
            dsum += p;
            av[u] = (_Float16)p;                        // A-frag element
        }
        acc = __builtin_amdgcn_mfma_f32_16x16x32_f16(av, bf, acc, 0, 0, 0);
    }

    // dsum: lane has partial for row m over its 8-j slots; sum across kq
    dsum += __shfl_xor(dsum, 16, 64);
    dsum += __shfl_xor(dsum, 32, 64);
    // now every lane with the same (l&15) holds row (l&15)'s sum for wave w

    __shared__ float olds[4][16][17];   // [wave][i][d] (+1 pad)
    __shared__ float denl[4][16];
    #pragma unroll
    for (int reg = 0; reg < 4; ++reg)
        olds[w][kq * 4 + reg][m] = acc[reg];   // C/D: col=l&15, row=4*kq+reg
    if (l < 16) denl[w][l] = dsum;
    __syncthreads();

    // cross-wave reduce + store: thread t -> (i = t>>4, d = t&15)
    {
        const int i = t >> 4, d = t & 15;
        const float o   = olds[0][i][d] + olds[1][i][d]
                        + olds[2][i][d] + olds[3][i][d];
        const float den = denl[0][i] + denl[1][i] + denl[2][i] + denl[3][i];
        ATT[(size_t)(bn0 + i0 + i) * 128 + hh * 16 + d] = o / den;
    }
}

// ---------------------------------------------------------------------------
// Kernel 3: out = ATT (B*N,128) @ Wo (128,128). 8 rows/block, 512 blocks.
// ---------------------------------------------------------------------------
__global__ __launch_bounds__(256) void out_kernel(
    const float* __restrict__ ATT, const float* __restrict__ Wo,
    float* __restrict__ out)
{
    __shared__ float al[8][128];
    const int t  = threadIdx.x;
    const int R0 = blockIdx.x * 8;
    {
        const int f = t * 4;
        *(float4*)(&al[0][0] + f) = *(const float4*)(ATT + (size_t)R0 * 128 + f);
    }
    __syncthreads();

    const int cq = t & 31, rq = t >> 5;
    const int c4 = cq * 4;
    float a0 = 0.f, a1 = 0.f, a2 = 0.f, a3 = 0.f;
    #pragma unroll 8
    for (int k = 0; k < 128; ++k) {
        const float4 wv = *(const float4*)(Wo + k * 128 + c4);
        const float a = al[rq][k];
        a0 += a * wv.x; a1 += a * wv.y; a2 += a * wv.z; a3 += a * wv.w;
    }
    float4 o; o.x = a0; o.y = a1; o.z = a2; o.w = a3;
    *(float4*)(out + (size_t)(R0 + rq) * 128 + c4) = o;
}

// ---------------------------------------------------------------------------
extern "C" void kernel_launch(void* const* d_in, const int* in_sizes, int n_in,
                              void* d_out, int out_size, void* d_ws, size_t ws_size,
                              hipStream_t stream) {
    const float* h    = (const float*)d_in[0];
    const int*   edge = (const int*)d_in[1];
    const float* Wa   = (const float*)d_in[2];
    const float* Wv   = (const float*)d_in[3];
    const float* Wo   = (const float*)d_in[4];
    const int*   lo   = (const int*)d_in[5];
    float*       out  = (float*)d_out;

    // Zero the full used ws extent EVERY call: makes each launch see the same
    // initial state (harness poisons ws with 0xAA between timed launches;
    // round-8 evidence showed launch-1-vs-later divergence = ws-state
    // sensitivity). ~3.4 MB ≈ 1 µs; graph-capture-legal (memset node).
    hipMemsetAsync(d_ws, 0, WS_BYTES, stream);

    float*     ws  = (float*)d_ws;
    float*     SIt = ws;                        // (H, B*N)      32768 f32
    float*     SJt = SIt + H_ * BN_;            //               32768 f32
    float*     ATT = SJt + H_ * BN_;            // (B*N, 128)   524288 f32
    _Float16*  VT  = (_Float16*)(ATT + (size_t)BN_ * 128);  // (B,H,16,N) f16

    prep_kernel<<<BN_ / 8, 256, 0, stream>>>(h, Wa, Wv, SIt, SJt, VT);
    attn_kernel<<<dim3(N_ / 16, H_, B_), 256, 0, stream>>>(SIt, SJt, VT, edge, Wa, lo, ATT);
    out_kernel<<<BN_ / 8, 256, 0, stream>>>(ATT, Wo, out);
}